// Round 3
// baseline (657.880 us; speedup 1.0000x reference)
//
#include <hip/hip_runtime.h>

#define T_    8
#define H_    28
#define W_    28
#define NSP   6272      // T*H*W
#define NTOKS 6273
#define DIM   192
#define HEADS 2
#define HD    96
#define SCALE_ 0.10206207261596575f   // 96^-0.5
#define EPS_  1e-5f

#define QT    16
#define KT    64
#define QB2   ((NTOKS + QT - 1) / QT)   // 393
#define NTILES_TOT 99                   // ceil(6273/64)
#define SPLIT_TILE 50                   // split0: [0,50), split1: [50,99)
#define KCH   160                       // extended K channels (96 + 64 one-hot)
#define VT_LD 6400                      // padded vbT row length (tokens)

using bf16x8 = __attribute__((ext_vector_type(8))) short;
using f32x4  = __attribute__((ext_vector_type(4))) float;
typedef unsigned short u16;
typedef unsigned int   u32;

__device__ __forceinline__ u16 f2b(float f) {   // fp32 -> bf16 bits, RNE
    u32 u = __builtin_bit_cast(u32, f);
    u += 0x7fffu + ((u >> 16) & 1u);
    return (u16)(u >> 16);
}

// async global->LDS 16B: LDS dest is wave-uniform base + lane*16 (m104)
__device__ __forceinline__ void async16(const void* g, void* l) {
    __builtin_amdgcn_global_load_lds(
        (const __attribute__((address_space(1))) u32*)g,
        (__attribute__((address_space(3))) u32*)l, 16, 0, 0);
}

// ---------------- Kernel 1: qkv = x @ qkv_w^T + qkv_b (16 rows/block) ----------------
__global__ __launch_bounds__(256) void qkv_gemm(
    const float* __restrict__ x, const float* __restrict__ w,
    const float* __restrict__ b, float* __restrict__ qkv)
{
    __shared__ float xs[16][DIM];
    int row0 = blockIdx.x * 16;
    int t = threadIdx.x;
    for (int i = t; i < 16 * DIM; i += 256) {
        int r = i / DIM, c = i % DIM;
        xs[r][c] = (row0 + r < NTOKS) ? x[(size_t)(row0 + r) * DIM + c] : 0.f;
    }
    __syncthreads();
    for (int rep = 0; rep < 3; ++rep) {
        int j = t + rep * 256;
        if (j >= 3 * DIM) break;
        const float4* wr = (const float4*)(w + (size_t)j * DIM);
        float acc[16];
        #pragma unroll
        for (int r = 0; r < 16; ++r) acc[r] = 0.f;
        for (int k4 = 0; k4 < DIM / 4; ++k4) {
            float4 wv = wr[k4];
            #pragma unroll
            for (int r = 0; r < 16; ++r) {
                acc[r] += xs[r][k4*4+0]*wv.x + xs[r][k4*4+1]*wv.y
                        + xs[r][k4*4+2]*wv.z + xs[r][k4*4+3]*wv.w;
            }
        }
        float bj = b[j];
        #pragma unroll
        for (int r = 0; r < 16; ++r) {
            int row = row0 + r;
            if (row < NTOKS) qkv[(size_t)row * 576 + j] = acc[r] + bj;
        }
    }
}

// ------------- Kernel 2: depthwise conv3d pool + LayerNorm (fused h x which) -------------
// grid = NTOKS, block = 640: tid<576 -> (h, which, c); tid>=576 -> one-hot writer
__global__ __launch_bounds__(640) void pool_ln(
    const float* __restrict__ qkv,
    const float* __restrict__ wq, const float* __restrict__ wk, const float* __restrict__ wv,
    const float* __restrict__ gq, const float* __restrict__ bq,
    const float* __restrict__ gk, const float* __restrict__ bk,
    const float* __restrict__ gv, const float* __restrict__ bv,
    float* __restrict__ qp, u16* __restrict__ qbb,
    u16* __restrict__ kx, u16* __restrict__ vbb)
{
    int tok = blockIdx.x;
    int tid = threadIdx.x;
    __shared__ float r1[6 * 96], r2[6 * 96];

    int h = 0, which = 0, c = 0, g = 0;
    float val = 0.f;
    if (tid < 576) {
        h = tid / 288;
        int r = tid % 288;
        which = r / 96;
        c = r % 96;
        g = h * 3 + which;
        const float* pw = which == 0 ? wq : (which == 1 ? wk : wv);
        int col = which * DIM + h * HD + c;
        if (tok == 0) {
            val = qkv[col];
        } else {
            int sp  = tok - 1;
            int tq  = sp / (H_ * W_);
            int rem = sp % (H_ * W_);
            int hq  = rem / W_;
            int wq_ = rem % W_;
            const float* wc = pw + c * 27;
            #pragma unroll
            for (int dt = -1; dt <= 1; ++dt) {
                int tt = tq + dt; if (tt < 0 || tt >= T_) continue;
                #pragma unroll
                for (int dy = -1; dy <= 1; ++dy) {
                    int yy = hq + dy; if (yy < 0 || yy >= H_) continue;
                    #pragma unroll
                    for (int dx = -1; dx <= 1; ++dx) {
                        int xx = wq_ + dx; if (xx < 0 || xx >= W_) continue;
                        int tok2 = 1 + (tt * H_ + yy) * W_ + xx;
                        val += wc[(dt+1)*9 + (dy+1)*3 + (dx+1)]
                             * qkv[(size_t)tok2 * 576 + col];
                    }
                }
            }
        }
        r1[g * 96 + c] = val;
        r2[g * 96 + c] = val * val;
    } else {
        // one-hot channels for kx (both heads)
        int j = tid - 576;           // 0..63
        u16 v = 0;
        if (tok >= 1) {
            int sp  = tok - 1;
            int kt  = sp / (H_ * W_);
            int rem = sp % (H_ * W_);
            int kh  = rem / W_;
            int kw  = rem % W_;
            int match = (j < 8) ? (j == kt) : (j < 36) ? (j - 8 == kh) : (j - 36 == kw);
            v = match ? (u16)0x3F80 : (u16)0;   // bf16 1.0
        }
        kx[((size_t)0 * NTOKS + tok) * KCH + 96 + j] = v;
        kx[((size_t)1 * NTOKS + tok) * KCH + 96 + j] = v;
    }
    __syncthreads();
    if (tid < 576 && c < 32) { r1[g*96+c] += r1[g*96+c+64]; r2[g*96+c] += r2[g*96+c+64]; }
    __syncthreads();
    for (int s = 32; s > 0; s >>= 1) {
        if (tid < 576 && c < s) { r1[g*96+c] += r1[g*96+c+s]; r2[g*96+c] += r2[g*96+c+s]; }
        __syncthreads();
    }
    if (tid < 576) {
        float m   = r1[g*96] * (1.f / HD);
        float var = r2[g*96] * (1.f / HD) - m * m;
        float inv = rsqrtf(var + EPS_);
        const float* gg = which == 0 ? gq : (which == 1 ? gk : gv);
        const float* bb = which == 0 ? bq : (which == 1 ? bk : bv);
        float o = (val - m) * inv * gg[c] + bb[c];
        size_t off = ((size_t)h * NTOKS + tok) * HD + c;
        if (which == 0)      { qp[off] = o; qbb[off] = f2b(o * SCALE_); }
        else if (which == 1) { kx[((size_t)h * NTOKS + tok) * KCH + c] = f2b(o); }
        else                 { vbb[off] = f2b(o); }
    }
}

// ------------- Kernel 2b: transpose V to [h][c][tok] (padded rows) -------------
__global__ __launch_bounds__(256) void vtrans(
    const u16* __restrict__ vbb, u16* __restrict__ vbT)
{
    __shared__ u16 tls[128][104];
    int h  = blockIdx.y;
    int t0 = blockIdx.x * 128;
    int tid = threadIdx.x;
    #pragma unroll
    for (int it = 0; it < 24; ++it) {           // 128*48 dwords
        int idx = tid + it * 256;
        int row = idx / 48, col = idx % 48;
        int tok = t0 + row; if (tok > NTOKS - 1) tok = NTOKS - 1;
        *(u32*)&tls[row][col*2] = *(const u32*)(vbb + ((size_t)h * NTOKS + tok) * HD + col*2);
    }
    __syncthreads();
    #pragma unroll
    for (int it = 0; it < 24; ++it) {           // 96*64 dwords
        int idx = tid + it * 256;
        int c = idx / 64, tp = idx % 64;
        u32 lo = tls[tp*2][c], hi = tls[tp*2+1][c];
        *(u32*)(vbT + ((size_t)h * HD + c) * VT_LD + t0 + tp*2) = lo | (hi << 16);
    }
}

// ------------- Kernel 3: rel-pos bias component dot products (float4) -------------
__global__ __launch_bounds__(64) void relbias(
    const float* __restrict__ qp,
    const float* __restrict__ rel_h, const float* __restrict__ rel_w,
    const float* __restrict__ rel_t,
    float* __restrict__ bt, float* __restrict__ bh, float* __restrict__ bw)
{
    int h  = blockIdx.x / NSP;
    int sp = blockIdx.x % NSP;
    __shared__ float4 qv4[24];
    int t = threadIdx.x;
    if (t < 24)
        qv4[t] = ((const float4*)(qp + ((size_t)h * NTOKS + sp + 1) * HD))[t];
    __syncthreads();
    int tq  = sp / (H_ * W_);
    int rem = sp % (H_ * W_);
    int hq  = rem / W_;
    int wq  = rem % W_;
    const float* row;
    float* outp;
    if (t < 8)       { row = rel_t + (size_t)(tq - t        + (T_ - 1)) * HD; outp = bt + ((size_t)h*NSP + sp)*8  + t;      }
    else if (t < 36) { row = rel_h + (size_t)(hq - (t - 8)  + (H_ - 1)) * HD; outp = bh + ((size_t)h*NSP + sp)*28 + (t-8);  }
    else             { row = rel_w + (size_t)(wq - (t - 36) + (W_ - 1)) * HD; outp = bw + ((size_t)h*NSP + sp)*28 + (t-36); }
    const float4* r4 = (const float4*)row;
    float acc = 0.f;
    #pragma unroll
    for (int i = 0; i < 24; ++i) {
        float4 a = qv4[i], b = r4[i];
        acc += a.x*b.x + a.y*b.y + a.z*b.z + a.w*b.w;
    }
    *outp = acc;
}

// ------------- Kernel 4: MFMA flash attention v2 -------------
// grid = (QB2, HEADS*2), block = 256 (4 waves). blockIdx.y: h = y>>1, split = y&1.
// Bias folded into MFMA via extended K channels; fixed-max softmax (m=0);
// staging via global_load_lds into fragment-contiguous slabs.
__global__ __launch_bounds__(256, 4) void attn_mfma2(
    const u16* __restrict__ qbb, const u16* __restrict__ kx,
    const u16* __restrict__ vbT,
    const float* __restrict__ btp, const float* __restrict__ bhp,
    const float* __restrict__ bwp,
    float* __restrict__ pO, float* __restrict__ pl)
{
    __shared__ __align__(16) u16 kls[20 * 512];   // [c5(5)][quad(4)][key(64)][8] = 20 KB
    __shared__ __align__(16) u16 vls[12 * 512];   // [kc(2)][quad(4)][n(96)][8]  = 12 KB
    __shared__ __align__(16) u16 pls[16 * 72];    // probs bf16 [q][key], pad 72
    __shared__ float biasL[16 * 64];
    __shared__ float lsumL[4][16];

    const int qb    = blockIdx.x;
    const int h     = blockIdx.y >> 1;
    const int split = blockIdx.y & 1;
    const int q0    = qb * QT;
    const int tid   = threadIdx.x;
    const int w     = tid >> 6;
    const int lane  = tid & 63;
    const int quad  = lane >> 4;
    const int l16   = lane & 15;

    // bias table for this block's 16 query rows
    for (int i = tid; i < QT * 64; i += 256) {
        int q = i >> 6, kk = i & 63;
        int tok = q0 + q;
        float v = 0.f;
        if (tok >= 1 && tok < NTOKS) {
            int sp = tok - 1;
            if (kk < 8)       v = btp[((size_t)h * NSP + sp) * 8  + kk];
            else if (kk < 36) v = bhp[((size_t)h * NSP + sp) * 28 + (kk - 8)];
            else              v = bwp[((size_t)h * NSP + sp) * 28 + (kk - 36)];
        }
        biasL[i] = v;
    }
    __syncthreads();

    // Q_ext fragments: chunks 0..2 = q*SCALE (bf16), chunks 3..4 = bias values
    bf16x8 aq[5];
    {
        int tok = q0 + l16; if (tok > NTOKS - 1) tok = NTOKS - 1;
        const u16* qrow = qbb + ((size_t)h * NTOKS + tok) * HD;
        #pragma unroll
        for (int cc = 0; cc < 3; ++cc)
            aq[cc] = *(const bf16x8*)(qrow + cc * 32 + quad * 8);
        #pragma unroll
        for (int cc = 3; cc < 5; ++cc) {
            bf16x8 tf;
            #pragma unroll
            for (int j = 0; j < 8; ++j)
                tf[j] = (short)f2b(biasL[l16 * 64 + (cc - 3) * 32 + quad * 8 + j]);
            aq[cc] = tf;
        }
    }

    f32x4 acc0 = {0,0,0,0}, acc1 = {0,0,0,0};
    const int nt0 = w, nt1 = w + 4;
    const bool has2 = (w < 2);
    float psum[4] = {0.f, 0.f, 0.f, 0.f};

    const int t0 = split ? SPLIT_TILE : 0;
    const int t1 = split ? NTILES_TOT : SPLIT_TILE;

    for (int tile = t0; tile < t1; ++tile) {
        const int kb0 = tile * KT;
        // ---- stage K (5 async/wave) + V^T (3 async/wave) ----
        {
            int key = kb0 + lane; if (key > NTOKS - 1) key = NTOKS - 1;
            const u16* gbase = kx + (size_t)((size_t)h * NTOKS + key) * KCH;
            #pragma unroll
            for (int i = 0; i < 5; ++i) {
                int CH = w * 5 + i;
                int c5 = CH >> 2, qd = CH & 3;
                async16(gbase + c5 * 32 + qd * 8, kls + CH * 512);
            }
            #pragma unroll
            for (int i = 0; i < 3; ++i) {
                int CH2 = w * 3 + i;
                int E = CH2 * 64 + lane;       // 0..767
                int kcq = E / 96, n = E - kcq * 96;
                int kc = kcq >> 2, qd = kcq & 3;
                const u16* src = vbT + ((size_t)h * HD + n) * VT_LD + kb0 + kc * 32 + qd * 8;
                async16(src, vls + CH2 * 512);
            }
        }
        __syncthreads();
        // ---- S = scale*QK^T + bias (via extended channels), 5 MFMA/wave ----
        f32x4 accs = {0,0,0,0};
        #pragma unroll
        for (int cc = 0; cc < 5; ++cc) {
            bf16x8 bk = *(const bf16x8*)(kls + (((cc * 4 + quad) * 64) + w * 16 + l16) * 8);
            accs = __builtin_amdgcn_mfma_f32_16x16x32_bf16(aq[cc], bk, accs, 0, 0, 0);
        }
        // ---- in-register fixed-max softmax: C col = key (w*16+l16), row = quad*4+rr ----
        {
            int keyg = kb0 + w * 16 + l16;
            bool ok = keyg < NTOKS;
            #pragma unroll
            for (int rr = 0; rr < 4; ++rr) {
                float p = ok ? __expf(accs[rr]) : 0.f;
                psum[rr] += p;
                pls[(quad * 4 + rr) * 72 + w * 16 + l16] = f2b(p);
            }
        }
        __syncthreads();
        // ---- PV: O += P V, wave w owns channel tiles nt0 (and nt1 if w<2) ----
        #pragma unroll
        for (int kc = 0; kc < 2; ++kc) {
            bf16x8 ap  = *(const bf16x8*)(pls + l16 * 72 + kc * 32 + quad * 8);
            bf16x8 bv0 = *(const bf16x8*)(vls + (((kc * 4 + quad) * 96) + nt0 * 16 + l16) * 8);
            acc0 = __builtin_amdgcn_mfma_f32_16x16x32_bf16(ap, bv0, acc0, 0, 0, 0);
            if (has2) {
                bf16x8 bv1 = *(const bf16x8*)(vls + (((kc * 4 + quad) * 96) + nt1 * 16 + l16) * 8);
                acc1 = __builtin_amdgcn_mfma_f32_16x16x32_bf16(ap, bv1, acc1, 0, 0, 0);
            }
        }
        __syncthreads();
    }

    // ---- final l reduction: per-thread psum -> across l16 -> across waves ----
    #pragma unroll
    for (int off = 1; off < 16; off <<= 1) {
        #pragma unroll
        for (int rr = 0; rr < 4; ++rr)
            psum[rr] += __shfl_xor(psum[rr], off);
    }
    if (l16 == 0) {
        #pragma unroll
        for (int rr = 0; rr < 4; ++rr)
            lsumL[w][quad * 4 + rr] = psum[rr];
    }
    __syncthreads();
    const int sh = split * HEADS + h;
    if (tid < QT) {
        int tok = q0 + tid;
        if (tok < NTOKS)
            pl[(size_t)sh * NTOKS + tok] =
                lsumL[0][tid] + lsumL[1][tid] + lsumL[2][tid] + lsumL[3][tid];
    }
    // ---- dump unnormalized O partials ----
    #pragma unroll
    for (int rr = 0; rr < 4; ++rr) {
        int tok = q0 + quad * 4 + rr;
        if (tok >= NTOKS) continue;
        pO[((size_t)sh * NTOKS + tok) * HD + nt0 * 16 + l16] = acc0[rr];
        if (has2)
            pO[((size_t)sh * NTOKS + tok) * HD + nt1 * 16 + l16] = acc1[rr];
    }
}

// ------------- Kernel 4b: combine k-split partials + residual -------------
__global__ __launch_bounds__(256) void combine(
    const float* __restrict__ pO, const float* __restrict__ pl,
    const float* __restrict__ qp, float* __restrict__ pre)
{
    int idx = blockIdx.x * 256 + threadIdx.x;
    if (idx >= NTOKS * DIM) return;
    int tok = idx / DIM, d = idx - tok * DIM;
    int h = d / HD, c = d - h * HD;
    size_t o0 = ((size_t)(0 * HEADS + h) * NTOKS + tok) * HD + c;
    size_t o1 = ((size_t)(1 * HEADS + h) * NTOKS + tok) * HD + c;
    float l = pl[(size_t)(0 * HEADS + h) * NTOKS + tok]
            + pl[(size_t)(1 * HEADS + h) * NTOKS + tok];
    float o = (pO[o0] + pO[o1]) / l;
    if (tok >= 1) o += qp[((size_t)h * NTOKS + tok) * HD + c];
    pre[idx] = o;
}

// ---------------- Kernel 5: out = pre @ proj_w^T + proj_b (16 rows/block) ----------------
__global__ __launch_bounds__(192) void proj_gemm(
    const float* __restrict__ pre, const float* __restrict__ w,
    const float* __restrict__ b, float* __restrict__ out)
{
    __shared__ float xs[16][DIM];
    int row0 = blockIdx.x * 16;
    int t = threadIdx.x;
    for (int i = t; i < 16 * DIM; i += 192) {
        int r = i / DIM, c = i % DIM;
        xs[r][c] = (row0 + r < NTOKS) ? pre[(size_t)(row0 + r) * DIM + c] : 0.f;
    }
    __syncthreads();
    int j = t;  // 0..191
    const float4* wr = (const float4*)(w + (size_t)j * DIM);
    float acc[16];
    #pragma unroll
    for (int r = 0; r < 16; ++r) acc[r] = 0.f;
    for (int k4 = 0; k4 < DIM / 4; ++k4) {
        float4 wv = wr[k4];
        #pragma unroll
        for (int r = 0; r < 16; ++r) {
            acc[r] += xs[r][k4*4+0]*wv.x + xs[r][k4*4+1]*wv.y
                    + xs[r][k4*4+2]*wv.z + xs[r][k4*4+3]*wv.w;
        }
    }
    float bj = b[j];
    #pragma unroll
    for (int r = 0; r < 16; ++r) {
        int row = row0 + r;
        if (row < NTOKS) out[(size_t)row * DIM + j] = acc[r] + bj;
    }
}

extern "C" void kernel_launch(void* const* d_in, const int* in_sizes, int n_in,
                              void* d_out, int out_size, void* d_ws, size_t ws_size,
                              hipStream_t stream) {
    (void)in_sizes; (void)n_in; (void)out_size; (void)ws_size;
    const float* x      = (const float*)d_in[0];
    const float* qkv_w  = (const float*)d_in[1];
    const float* qkv_b  = (const float*)d_in[2];
    const float* proj_w = (const float*)d_in[3];
    const float* proj_b = (const float*)d_in[4];
    const float* pool_q = (const float*)d_in[5];
    const float* pool_k = (const float*)d_in[6];
    const float* pool_v = (const float*)d_in[7];
    const float* gq     = (const float*)d_in[8];
    const float* bq     = (const float*)d_in[9];
    const float* gk     = (const float*)d_in[10];
    const float* bk     = (const float*)d_in[11];
    const float* gv     = (const float*)d_in[12];
    const float* bv     = (const float*)d_in[13];
    const float* rel_h  = (const float*)d_in[14];
    const float* rel_w  = (const float*)d_in[15];
    const float* rel_t  = (const float*)d_in[16];

    char* p = (char*)d_ws;
    auto alloc = [&](size_t bytes) -> void* {
        void* r = (void*)p; p += (bytes + 255) & ~(size_t)255; return r;
    };
    float* qkv = (float*)alloc((size_t)NTOKS * 576 * 4);
    float* qp  = (float*)alloc((size_t)HEADS * NTOKS * HD * 4);
    u16*   qbb = (u16*)  alloc((size_t)HEADS * NTOKS * HD * 2);
    u16*   kxb = (u16*)  alloc((size_t)HEADS * NTOKS * KCH * 2);
    u16*   vbb = (u16*)  alloc((size_t)HEADS * NTOKS * HD * 2);
    u16*   vbT = (u16*)  alloc((size_t)HEADS * HD * VT_LD * 2);
    float* bt  = (float*)alloc((size_t)HEADS * NSP * 8 * 4);
    float* bh  = (float*)alloc((size_t)HEADS * NSP * 28 * 4);
    float* bw  = (float*)alloc((size_t)HEADS * NSP * 28 * 4);
    float* pO  = (float*)alloc((size_t)2 * HEADS * NTOKS * HD * 4);
    float* pl  = (float*)alloc((size_t)2 * HEADS * NTOKS * 4);
    float* pre = (float*)alloc((size_t)NTOKS * DIM * 4);

    qkv_gemm<<<(NTOKS + 15) / 16, 256, 0, stream>>>(x, qkv_w, qkv_b, qkv);
    pool_ln<<<NTOKS, 640, 0, stream>>>(
        qkv, pool_q, pool_k, pool_v, gq, bq, gk, bk, gv, bv, qp, qbb, kxb, vbb);
    vtrans<<<dim3((NTOKS + 127) / 128, HEADS), 256, 0, stream>>>(vbb, vbT);
    relbias<<<HEADS * NSP, 64, 0, stream>>>(qp, rel_h, rel_w, rel_t, bt, bh, bw);
    attn_mfma2<<<dim3(QB2, HEADS * 2), 256, 0, stream>>>(
        qbb, kxb, vbT, bt, bh, bw, pO, pl);
    combine<<<(NTOKS * DIM + 255) / 256, 256, 0, stream>>>(pO, pl, qp, pre);
    proj_gemm<<<(NTOKS + 15) / 16, 192, 0, stream>>>(pre, proj_w, proj_b, (float*)d_out);
}

// Round 4
// 468.155 us; speedup vs baseline: 1.4053x; 1.4053x over previous
//
#include <hip/hip_runtime.h>

#define T_    8
#define H_    28
#define W_    28
#define NSP   6272      // T*H*W
#define NTOKS 6273
#define DIM   192
#define HEADS 2
#define HD    96
#define SCALE_ 0.10206207261596575f   // 96^-0.5
#define EPS_  1e-5f

#define QT    64
#define KT    64
#define QB3   99                        // ceil(6273/64)
#define NTILES_TOT 99                   // ceil(6273/64)
#define NSPL  4                         // k-split
#define KCH   160                       // extended K channels (96 + 64 one-hot)
#define VT_LD 6400                      // padded vbT row length (tokens)

using bf16x8 = __attribute__((ext_vector_type(8))) short;
using f32x4  = __attribute__((ext_vector_type(4))) float;
typedef unsigned short u16;
typedef unsigned int   u32;

__device__ __forceinline__ u16 f2b(float f) {   // fp32 -> bf16 bits, RNE
    u32 u = __builtin_bit_cast(u32, f);
    u += 0x7fffu + ((u >> 16) & 1u);
    return (u16)(u >> 16);
}

// async global->LDS 16B: LDS dest is wave-uniform base + lane*16 (m104)
__device__ __forceinline__ void async16(const void* g, void* l) {
    __builtin_amdgcn_global_load_lds(
        (const __attribute__((address_space(1))) u32*)g,
        (__attribute__((address_space(3))) u32*)l, 16, 0, 0);
}

// ---------------- Kernel 1: qkv = x @ qkv_w^T + qkv_b (16 rows/block) ----------------
__global__ __launch_bounds__(256) void qkv_gemm(
    const float* __restrict__ x, const float* __restrict__ w,
    const float* __restrict__ b, float* __restrict__ qkv)
{
    __shared__ float xs[16][DIM];
    int row0 = blockIdx.x * 16;
    int t = threadIdx.x;
    for (int i = t; i < 16 * DIM; i += 256) {
        int r = i / DIM, c = i % DIM;
        xs[r][c] = (row0 + r < NTOKS) ? x[(size_t)(row0 + r) * DIM + c] : 0.f;
    }
    __syncthreads();
    for (int rep = 0; rep < 3; ++rep) {
        int j = t + rep * 256;
        if (j >= 3 * DIM) break;
        const float4* wr = (const float4*)(w + (size_t)j * DIM);
        float acc[16];
        #pragma unroll
        for (int r = 0; r < 16; ++r) acc[r] = 0.f;
        for (int k4 = 0; k4 < DIM / 4; ++k4) {
            float4 wv = wr[k4];
            #pragma unroll
            for (int r = 0; r < 16; ++r) {
                acc[r] += xs[r][k4*4+0]*wv.x + xs[r][k4*4+1]*wv.y
                        + xs[r][k4*4+2]*wv.z + xs[r][k4*4+3]*wv.w;
            }
        }
        float bj = b[j];
        #pragma unroll
        for (int r = 0; r < 16; ++r) {
            int row = row0 + r;
            if (row < NTOKS) qkv[(size_t)row * 576 + j] = acc[r] + bj;
        }
    }
}

// ------------- Kernel 2: depthwise conv3d pool + LayerNorm (R2 shape) -------------
// grid.x = HEADS*NTOKS, grid.y = 3 (q,k,v), block = 128
__global__ __launch_bounds__(128) void pool_ln(
    const float* __restrict__ qkv,
    const float* __restrict__ wq, const float* __restrict__ wk, const float* __restrict__ wv,
    const float* __restrict__ gq, const float* __restrict__ bq,
    const float* __restrict__ gk, const float* __restrict__ bk,
    const float* __restrict__ gv, const float* __restrict__ bv,
    float* __restrict__ qp, u16* __restrict__ qbb,
    u16* __restrict__ kx, u16* __restrict__ vbb)
{
    int which = blockIdx.y;
    const float* pw = which == 0 ? wq : (which == 1 ? wk : wv);
    const float* g  = which == 0 ? gq : (which == 1 ? gk : gv);
    const float* bb = which == 0 ? bq : (which == 1 ? bk : bv);

    int h   = blockIdx.x / NTOKS;
    int tok = blockIdx.x % NTOKS;
    int c   = threadIdx.x;

    float val = 0.f;
    if (c < HD) {
        int base_col = which * DIM + h * HD + c;
        if (tok == 0) {
            val = qkv[base_col];
        } else {
            int sp  = tok - 1;
            int tq  = sp / (H_ * W_);
            int rem = sp % (H_ * W_);
            int hq  = rem / W_;
            int wq_ = rem % W_;
            const float* wc = pw + c * 27;
            #pragma unroll
            for (int dt = -1; dt <= 1; ++dt) {
                int tt = tq + dt; if (tt < 0 || tt >= T_) continue;
                #pragma unroll
                for (int dy = -1; dy <= 1; ++dy) {
                    int yy = hq + dy; if (yy < 0 || yy >= H_) continue;
                    #pragma unroll
                    for (int dx = -1; dx <= 1; ++dx) {
                        int xx = wq_ + dx; if (xx < 0 || xx >= W_) continue;
                        int tok2 = 1 + (tt * H_ + yy) * W_ + xx;
                        val += wc[(dt+1)*9 + (dy+1)*3 + (dx+1)]
                             * qkv[(size_t)tok2 * 576 + base_col];
                    }
                }
            }
        }
    }
    __shared__ float r1[128], r2[128];
    r1[threadIdx.x] = (c < HD) ? val : 0.f;
    r2[threadIdx.x] = (c < HD) ? val * val : 0.f;
    __syncthreads();
    for (int s = 64; s > 0; s >>= 1) {
        if (threadIdx.x < s) { r1[threadIdx.x] += r1[threadIdx.x+s]; r2[threadIdx.x] += r2[threadIdx.x+s]; }
        __syncthreads();
    }
    float m   = r1[0] * (1.f / HD);
    float var = r2[0] * (1.f / HD) - m * m;
    float inv = rsqrtf(var + EPS_);
    if (c < HD) {
        float o = (val - m) * inv * g[c] + bb[c];
        size_t off = ((size_t)h * NTOKS + tok) * HD + c;
        if (which == 0)      { qp[off] = o; qbb[off] = f2b(o * SCALE_); }
        else if (which == 1) { kx[((size_t)h * NTOKS + tok) * KCH + c] = f2b(o); }
        else                 { vbb[off] = f2b(o); }
    }
}

// ------------- Kernel 2b: transpose V to [h][c][tok] + write one-hot K channels -------------
// grid = (ceil(NTOKS/128), HEADS), block = 256
__global__ __launch_bounds__(256) void vtrans(
    const u16* __restrict__ vbb, u16* __restrict__ vbT, u16* __restrict__ kx)
{
    __shared__ u16 tls[128][104];
    int h  = blockIdx.y;
    int t0 = blockIdx.x * 128;
    int tid = threadIdx.x;
    #pragma unroll
    for (int it = 0; it < 24; ++it) {           // 128*48 dwords
        int idx = tid + it * 256;
        int row = idx / 48, col = idx % 48;
        int tok = t0 + row; if (tok > NTOKS - 1) tok = NTOKS - 1;
        *(u32*)&tls[row][col*2] = *(const u32*)(vbb + ((size_t)h * NTOKS + tok) * HD + col*2);
    }
    __syncthreads();
    #pragma unroll
    for (int it = 0; it < 24; ++it) {           // 96*64 dwords
        int idx = tid + it * 256;
        int c = idx / 64, tp = idx % 64;
        u32 lo = tls[tp*2][c], hi = tls[tp*2+1][c];
        *(u32*)(vbT + ((size_t)h * HD + c) * VT_LD + t0 + tp*2) = lo | (hi << 16);
    }
    // one-hot bias channels for this head's kx rows
    #pragma unroll
    for (int it = 0; it < 32; ++it) {           // 128*64 u16
        int i = tid + it * 256;
        int tok = t0 + (i >> 6);
        int j = i & 63;
        if (tok >= NTOKS) continue;
        u16 v = 0;
        if (tok >= 1) {
            int sp  = tok - 1;
            int kt  = sp / (H_ * W_);
            int rem = sp % (H_ * W_);
            int kh  = rem / W_;
            int kw  = rem % W_;
            int match = (j < 8) ? (j == kt) : (j < 36) ? (j - 8 == kh) : (j - 36 == kw);
            v = match ? (u16)0x3F80 : (u16)0;   // bf16 1.0
        }
        kx[((size_t)h * NTOKS + tok) * KCH + 96 + j] = v;
    }
}

// ------------- Kernel 3: rel-pos bias component dot products (float4) -------------
__global__ __launch_bounds__(64) void relbias(
    const float* __restrict__ qp,
    const float* __restrict__ rel_h, const float* __restrict__ rel_w,
    const float* __restrict__ rel_t,
    float* __restrict__ bt, float* __restrict__ bh, float* __restrict__ bw)
{
    int h  = blockIdx.x / NSP;
    int sp = blockIdx.x % NSP;
    __shared__ float4 qv4[24];
    int t = threadIdx.x;
    if (t < 24)
        qv4[t] = ((const float4*)(qp + ((size_t)h * NTOKS + sp + 1) * HD))[t];
    __syncthreads();
    int tq  = sp / (H_ * W_);
    int rem = sp % (H_ * W_);
    int hq  = rem / W_;
    int wq  = rem % W_;
    const float* row;
    float* outp;
    if (t < 8)       { row = rel_t + (size_t)(tq - t        + (T_ - 1)) * HD; outp = bt + ((size_t)h*NSP + sp)*8  + t;      }
    else if (t < 36) { row = rel_h + (size_t)(hq - (t - 8)  + (H_ - 1)) * HD; outp = bh + ((size_t)h*NSP + sp)*28 + (t-8);  }
    else             { row = rel_w + (size_t)(wq - (t - 36) + (W_ - 1)) * HD; outp = bw + ((size_t)h*NSP + sp)*28 + (t-36); }
    const float4* r4 = (const float4*)row;
    float acc = 0.f;
    #pragma unroll
    for (int i = 0; i < 24; ++i) {
        float4 a = qv4[i], b = r4[i];
        acc += a.x*b.x + a.y*b.y + a.z*b.z + a.w*b.w;
    }
    *outp = acc;
}

// ------------- Kernel 4: MFMA flash attention v3 (QT=64, XCD-pinned k-split) -------------
// grid.x = QB3*8; g=blockIdx.x&7 -> (h = g>>2, split = g&3); qb = blockIdx.x>>3.
// 4 waves; wave w owns queries q0+w*16..+15 (M-split). K/V staged once per tile, shared.
// Bias folded into MFMA via extended K channels; fixed-max softmax (m=0).
__global__ __launch_bounds__(256, 3) void attn_mfma3(
    const u16* __restrict__ qbb, const u16* __restrict__ kx,
    const u16* __restrict__ vbT,
    const float* __restrict__ btp, const float* __restrict__ bhp,
    const float* __restrict__ bwp,
    float* __restrict__ pO, float* __restrict__ pl)
{
    __shared__ __align__(16) u16 kls[20 * 512];   // [CH=cc*4+quad][key(64)][8] = 20 KB
    __shared__ __align__(16) u16 vls[12 * 512];   // [(kc*4+quad)*96 + n][8]    = 12 KB
    __shared__ __align__(16) u16 pls[64 * 72];    // P bf16 [q(64)][key(64) pad 72] = 9 KB
    __shared__ __align__(16) u16 biasB[64 * 64];  // bias bf16 [q][idx] = 8 KB

    const int g     = blockIdx.x & 7;
    const int qb    = blockIdx.x >> 3;
    const int h     = g >> 2;
    const int split = g & 3;
    const int q0    = qb * QT;
    const int tid   = threadIdx.x;
    const int w     = tid >> 6;
    const int lane  = tid & 63;
    const int quad  = lane >> 4;
    const int l16   = lane & 15;

    // bias table (bf16) for this block's 64 query rows
    for (int i = tid; i < 64 * 64; i += 256) {
        int q = i >> 6, kk = i & 63;
        int tok = q0 + q;
        float v = 0.f;
        if (tok >= 1 && tok < NTOKS) {
            int sp = tok - 1;
            if (kk < 8)       v = btp[((size_t)h * NSP + sp) * 8  + kk];
            else if (kk < 36) v = bhp[((size_t)h * NSP + sp) * 28 + (kk - 8)];
            else              v = bwp[((size_t)h * NSP + sp) * 28 + (kk - 36)];
        }
        biasB[i] = f2b(v);
    }
    __syncthreads();

    // A fragments for wave w's queries: chunks 0..2 = q*SCALE, 3..4 = bias
    bf16x8 aq[5];
    {
        int tok = q0 + w * 16 + l16; if (tok > NTOKS - 1) tok = NTOKS - 1;
        const u16* qrow = qbb + ((size_t)h * NTOKS + tok) * HD;
        #pragma unroll
        for (int cc = 0; cc < 3; ++cc)
            aq[cc] = *(const bf16x8*)(qrow + cc * 32 + quad * 8);
        #pragma unroll
        for (int cc = 3; cc < 5; ++cc)
            aq[cc] = *(const bf16x8*)(biasB + (w * 16 + l16) * 64 + (cc - 3) * 32 + quad * 8);
    }

    f32x4 accO[6];
    #pragma unroll
    for (int nt = 0; nt < 6; ++nt) accO[nt] = (f32x4){0,0,0,0};
    float psum[4] = {0.f, 0.f, 0.f, 0.f};

    const int t0 = split * 25;
    const int t1 = (t0 + 25 < NTILES_TOT) ? t0 + 25 : NTILES_TOT;

    for (int tile = t0; tile < t1; ++tile) {
        const int kb0 = tile * KT;
        // ---- stage K (5 async/wave) + V^T (3 async/wave) ----
        {
            int key = kb0 + lane; if (key > NTOKS - 1) key = NTOKS - 1;
            const u16* gbase = kx + ((size_t)h * NTOKS + key) * KCH;
            #pragma unroll
            for (int i = 0; i < 5; ++i) {
                int CH = w * 5 + i;
                int c5 = CH >> 2, qd = CH & 3;
                async16(gbase + c5 * 32 + qd * 8, kls + CH * 512);
            }
            #pragma unroll
            for (int i = 0; i < 3; ++i) {
                int CH2 = w * 3 + i;
                int E = CH2 * 64 + lane;       // 0..767
                int kcq = E / 96, n = E - kcq * 96;
                int kc = kcq >> 2, qd = kcq & 3;
                const u16* src = vbT + ((size_t)h * HD + n) * VT_LD + kb0 + kc * 32 + qd * 8;
                async16(src, vls + CH2 * 512);
            }
        }
        __syncthreads();
        // ---- S = scale*QK^T + bias: 4 n-tiles x 5 chunks = 20 MFMA/wave ----
        f32x4 sacc[4];
        #pragma unroll
        for (int nt = 0; nt < 4; ++nt) sacc[nt] = (f32x4){0,0,0,0};
        #pragma unroll
        for (int cc = 0; cc < 5; ++cc) {
            #pragma unroll
            for (int nt = 0; nt < 4; ++nt) {
                bf16x8 bk = *(const bf16x8*)(kls + (((cc * 4 + quad) * 64) + nt * 16 + l16) * 8);
                sacc[nt] = __builtin_amdgcn_mfma_f32_16x16x32_bf16(aq[cc], bk, sacc[nt], 0, 0, 0);
            }
        }
        // ---- fixed-max softmax in-register; write wave-private P rows ----
        #pragma unroll
        for (int nt = 0; nt < 4; ++nt) {
            int keyg = kb0 + nt * 16 + l16;
            bool ok = keyg < NTOKS;
            #pragma unroll
            for (int rr = 0; rr < 4; ++rr) {
                float p = ok ? __expf(sacc[nt][rr]) : 0.f;
                psum[rr] += p;
                pls[(w * 16 + quad * 4 + rr) * 72 + nt * 16 + l16] = f2b(p);
            }
        }
        // no barrier needed: pls rows are wave-private; lgkmcnt orders ds ops
        // ---- PV: 6 n-tiles x 2 k-chunks = 12 MFMA/wave ----
        #pragma unroll
        for (int kc = 0; kc < 2; ++kc) {
            bf16x8 ap = *(const bf16x8*)(pls + (w * 16 + l16) * 72 + kc * 32 + quad * 8);
            #pragma unroll
            for (int nt = 0; nt < 6; ++nt) {
                bf16x8 bv = *(const bf16x8*)(vls + (((kc * 4 + quad) * 96) + nt * 16 + l16) * 8);
                accO[nt] = __builtin_amdgcn_mfma_f32_16x16x32_bf16(ap, bv, accO[nt], 0, 0, 0);
            }
        }
        __syncthreads();   // protect kls/vls before next tile's staging
    }

    // ---- l reduction across the 16 lanes sharing a row-group ----
    #pragma unroll
    for (int off = 1; off < 16; off <<= 1) {
        #pragma unroll
        for (int rr = 0; rr < 4; ++rr)
            psum[rr] += __shfl_xor(psum[rr], off);
    }
    const int sh = split * HEADS + h;
    if (l16 == 0) {
        #pragma unroll
        for (int rr = 0; rr < 4; ++rr) {
            int tok = q0 + w * 16 + quad * 4 + rr;
            if (tok < NTOKS)
                pl[(size_t)sh * NTOKS + tok] = psum[rr];
        }
    }
    // ---- dump unnormalized O partials (C layout: col=channel, row=query) ----
    #pragma unroll
    for (int rr = 0; rr < 4; ++rr) {
        int tok = q0 + w * 16 + quad * 4 + rr;
        if (tok >= NTOKS) continue;
        #pragma unroll
        for (int nt = 0; nt < 6; ++nt)
            pO[((size_t)sh * NTOKS + tok) * HD + nt * 16 + l16] = accO[nt][rr];
    }
}

// ------- Kernel 5: fused combine + residual + proj GEMM (16 rows/block) -------
__global__ __launch_bounds__(192) void proj_gemm(
    const float* __restrict__ pO, const float* __restrict__ pl,
    const float* __restrict__ qp,
    const float* __restrict__ w, const float* __restrict__ b,
    float* __restrict__ out)
{
    __shared__ float xs[16][DIM];
    int row0 = blockIdx.x * 16;
    int t = threadIdx.x;
    for (int i = t; i < 16 * DIM; i += 192) {
        int r = i / DIM, c = i % DIM;
        int tok = row0 + r;
        float val = 0.f;
        if (tok < NTOKS) {
            int hh = c / HD, cc = c - hh * HD;
            float l = 0.f, o = 0.f;
            #pragma unroll
            for (int s = 0; s < NSPL; ++s) {
                l += pl[(size_t)(s * HEADS + hh) * NTOKS + tok];
                o += pO[((size_t)(s * HEADS + hh) * NTOKS + tok) * HD + cc];
            }
            val = o / l;
            if (tok >= 1) val += qp[((size_t)hh * NTOKS + tok) * HD + cc];
        }
        xs[r][c] = val;
    }
    __syncthreads();
    int j = t;  // 0..191
    const float4* wr = (const float4*)(w + (size_t)j * DIM);
    float acc[16];
    #pragma unroll
    for (int r = 0; r < 16; ++r) acc[r] = 0.f;
    for (int k4 = 0; k4 < DIM / 4; ++k4) {
        float4 wv = wr[k4];
        #pragma unroll
        for (int r = 0; r < 16; ++r) {
            acc[r] += xs[r][k4*4+0]*wv.x + xs[r][k4*4+1]*wv.y
                    + xs[r][k4*4+2]*wv.z + xs[r][k4*4+3]*wv.w;
        }
    }
    float bj = b[j];
    #pragma unroll
    for (int r = 0; r < 16; ++r) {
        int row = row0 + r;
        if (row < NTOKS) out[(size_t)row * DIM + j] = acc[r] + bj;
    }
}

extern "C" void kernel_launch(void* const* d_in, const int* in_sizes, int n_in,
                              void* d_out, int out_size, void* d_ws, size_t ws_size,
                              hipStream_t stream) {
    (void)in_sizes; (void)n_in; (void)out_size; (void)ws_size;
    const float* x      = (const float*)d_in[0];
    const float* qkv_w  = (const float*)d_in[1];
    const float* qkv_b  = (const float*)d_in[2];
    const float* proj_w = (const float*)d_in[3];
    const float* proj_b = (const float*)d_in[4];
    const float* pool_q = (const float*)d_in[5];
    const float* pool_k = (const float*)d_in[6];
    const float* pool_v = (const float*)d_in[7];
    const float* gq     = (const float*)d_in[8];
    const float* bq     = (const float*)d_in[9];
    const float* gk     = (const float*)d_in[10];
    const float* bk     = (const float*)d_in[11];
    const float* gv     = (const float*)d_in[12];
    const float* bv     = (const float*)d_in[13];
    const float* rel_h  = (const float*)d_in[14];
    const float* rel_w  = (const float*)d_in[15];
    const float* rel_t  = (const float*)d_in[16];

    char* p = (char*)d_ws;
    auto alloc = [&](size_t bytes) -> void* {
        void* r = (void*)p; p += (bytes + 255) & ~(size_t)255; return r;
    };
    float* qkv = (float*)alloc((size_t)NTOKS * 576 * 4);
    float* qp  = (float*)alloc((size_t)HEADS * NTOKS * HD * 4);
    u16*   qbb = (u16*)  alloc((size_t)HEADS * NTOKS * HD * 2);
    u16*   kxb = (u16*)  alloc((size_t)HEADS * NTOKS * KCH * 2);
    u16*   vbb = (u16*)  alloc((size_t)HEADS * NTOKS * HD * 2);
    u16*   vbT = (u16*)  alloc((size_t)HEADS * HD * VT_LD * 2);
    float* bt  = (float*)alloc((size_t)HEADS * NSP * 8 * 4);
    float* bh  = (float*)alloc((size_t)HEADS * NSP * 28 * 4);
    float* bw  = (float*)alloc((size_t)HEADS * NSP * 28 * 4);
    float* pO  = (float*)alloc((size_t)NSPL * HEADS * NTOKS * HD * 4);
    float* pl  = (float*)alloc((size_t)NSPL * HEADS * NTOKS * 4);

    qkv_gemm<<<(NTOKS + 15) / 16, 256, 0, stream>>>(x, qkv_w, qkv_b, qkv);
    pool_ln<<<dim3(HEADS * NTOKS, 3), 128, 0, stream>>>(
        qkv, pool_q, pool_k, pool_v, gq, bq, gk, bk, gv, bv, qp, qbb, kxb, vbb);
    vtrans<<<dim3((NTOKS + 127) / 128, HEADS), 256, 0, stream>>>(vbb, vbT, kxb);
    relbias<<<HEADS * NSP, 64, 0, stream>>>(qp, rel_h, rel_w, rel_t, bt, bh, bw);
    attn_mfma3<<<QB3 * 8, 256, 0, stream>>>(qbb, kxb, vbT, bt, bh, bw, pO, pl);
    proj_gemm<<<(NTOKS + 15) / 16, 192, 0, stream>>>(pO, pl, qp, proj_w, proj_b, (float*)d_out);
}

// Round 5
// 373.933 us; speedup vs baseline: 1.7594x; 1.2520x over previous
//
#include <hip/hip_runtime.h>

#define T_    8
#define H_    28
#define W_    28
#define NSP   6272      // T*H*W
#define NTOKS 6273
#define DIM   192
#define HEADS 2
#define HD    96
#define SCALE_ 0.10206207261596575f   // 96^-0.5
#define EPS_  1e-5f

#define QT    64
#define KT    64
#define QB3   99                        // ceil(6273/64)
#define NTILES_TOT 99
#define NSPL  4                         // k-split
#define KCH   160                       // extended K channels (96 + 64 one-hot)
#define VT_LD 6400                      // padded vbT row length (tokens)

using bf16x8 = __attribute__((ext_vector_type(8))) short;
using f32x4  = __attribute__((ext_vector_type(4))) float;
typedef unsigned short u16;
typedef unsigned int   u32;

__device__ __forceinline__ u16 f2b(float f) {   // fp32 -> bf16 bits, RNE
    u32 u = __builtin_bit_cast(u32, f);
    u += 0x7fffu + ((u >> 16) & 1u);
    return (u16)(u >> 16);
}

// async global->LDS 16B: LDS dest is wave-uniform base + lane*16 (m104)
__device__ __forceinline__ void async16(const void* g, void* l) {
    __builtin_amdgcn_global_load_lds(
        (const __attribute__((address_space(1))) u32*)g,
        (__attribute__((address_space(3))) u32*)l, 16, 0, 0);
}

// ---------------- Kernel 0: fp32 -> bf16 conversion (x, qkv_w, proj_w) ----------------
__global__ __launch_bounds__(256) void cvt_bf16(
    const float* __restrict__ s0, u16* __restrict__ d0, int n0,
    const float* __restrict__ s1, u16* __restrict__ d1, int n1,
    const float* __restrict__ s2, u16* __restrict__ d2, int n2)
{
    int tot = n0 + n1 + n2;
    for (int i = blockIdx.x * 256 + threadIdx.x; i < tot; i += gridDim.x * 256) {
        if (i < n0)            d0[i] = f2b(s0[i]);
        else if (i < n0 + n1)  d1[i - n0] = f2b(s1[i - n0]);
        else                   d2[i - n0 - n1] = f2b(s2[i - n0 - n1]);
    }
}

// ---------------- Kernel 1: OUT[m][n] = sum_k A[m][k]*W[n][k] + bias[n] (MFMA) --------
// A bf16 [M][192], W bf16 [Ntot][192], OUT fp32 [M][ldo]. grid = (ceil(M/64), Ntot/64).
__global__ __launch_bounds__(256, 3) void gemm_bf16(
    const u16* __restrict__ A, const u16* __restrict__ Wt,
    const float* __restrict__ bias, float* __restrict__ out,
    int M, int ldo)
{
    __shared__ __align__(16) u16 als[24 * 512];
    __shared__ __align__(16) u16 wls[24 * 512];
    const int m0 = blockIdx.x * 64, n0 = blockIdx.y * 64;
    const int tid  = threadIdx.x;
    const int w    = tid >> 6;
    const int lane = tid & 63;
    const int quad = lane >> 4;
    const int l16  = lane & 15;
    {
        int m = m0 + lane; if (m > M - 1) m = M - 1;
        const u16* ab = A  + (size_t)m * 192;
        const u16* wb = Wt + (size_t)(n0 + lane) * 192;
        #pragma unroll
        for (int i = 0; i < 6; ++i) {
            int g = w * 6 + i;              // 0..23, covers k = g*8..g*8+7
            async16(ab + g * 8, als + g * 512);
            async16(wb + g * 8, wls + g * 512);
        }
    }
    __syncthreads();
    f32x4 acc[4];
    #pragma unroll
    for (int mt = 0; mt < 4; ++mt) acc[mt] = (f32x4){0,0,0,0};
    #pragma unroll
    for (int cc = 0; cc < 6; ++cc) {
        bf16x8 bf = *(const bf16x8*)(wls + (((cc * 4 + quad) * 64) + w * 16 + l16) * 8);
        #pragma unroll
        for (int mt = 0; mt < 4; ++mt) {
            bf16x8 af = *(const bf16x8*)(als + (((cc * 4 + quad) * 64) + mt * 16 + l16) * 8);
            acc[mt] = __builtin_amdgcn_mfma_f32_16x16x32_bf16(af, bf, acc[mt], 0, 0, 0);
        }
    }
    float bj = bias[n0 + w * 16 + l16];
    #pragma unroll
    for (int mt = 0; mt < 4; ++mt) {
        #pragma unroll
        for (int rr = 0; rr < 4; ++rr) {
            int row = m0 + mt * 16 + quad * 4 + rr;
            if (row < M)
                out[(size_t)row * ldo + n0 + w * 16 + l16] = acc[mt][rr] + bj;
        }
    }
}

// ------------- Kernel 2: depthwise conv3d pool + LayerNorm -------------
__global__ __launch_bounds__(128) void pool_ln(
    const float* __restrict__ qkv,
    const float* __restrict__ wq, const float* __restrict__ wk, const float* __restrict__ wv,
    const float* __restrict__ gq, const float* __restrict__ bq,
    const float* __restrict__ gk, const float* __restrict__ bk,
    const float* __restrict__ gv, const float* __restrict__ bv,
    float* __restrict__ qp, u16* __restrict__ qbb,
    u16* __restrict__ kx, u16* __restrict__ vbb)
{
    int which = blockIdx.y;
    const float* pw = which == 0 ? wq : (which == 1 ? wk : wv);
    const float* g  = which == 0 ? gq : (which == 1 ? gk : gv);
    const float* bb = which == 0 ? bq : (which == 1 ? bk : bv);

    int h   = blockIdx.x / NTOKS;
    int tok = blockIdx.x % NTOKS;
    int c   = threadIdx.x;

    float val = 0.f;
    if (c < HD) {
        int base_col = which * DIM + h * HD + c;
        if (tok == 0) {
            val = qkv[base_col];
        } else {
            int sp  = tok - 1;
            int tq  = sp / (H_ * W_);
            int rem = sp % (H_ * W_);
            int hq  = rem / W_;
            int wq_ = rem % W_;
            const float* wc = pw + c * 27;
            #pragma unroll
            for (int dt = -1; dt <= 1; ++dt) {
                int tt = tq + dt; if (tt < 0 || tt >= T_) continue;
                #pragma unroll
                for (int dy = -1; dy <= 1; ++dy) {
                    int yy = hq + dy; if (yy < 0 || yy >= H_) continue;
                    #pragma unroll
                    for (int dx = -1; dx <= 1; ++dx) {
                        int xx = wq_ + dx; if (xx < 0 || xx >= W_) continue;
                        int tok2 = 1 + (tt * H_ + yy) * W_ + xx;
                        val += wc[(dt+1)*9 + (dy+1)*3 + (dx+1)]
                             * qkv[(size_t)tok2 * 576 + base_col];
                    }
                }
            }
        }
    }
    __shared__ float r1[128], r2[128];
    r1[threadIdx.x] = (c < HD) ? val : 0.f;
    r2[threadIdx.x] = (c < HD) ? val * val : 0.f;
    __syncthreads();
    for (int s = 64; s > 0; s >>= 1) {
        if (threadIdx.x < s) { r1[threadIdx.x] += r1[threadIdx.x+s]; r2[threadIdx.x] += r2[threadIdx.x+s]; }
        __syncthreads();
    }
    float m   = r1[0] * (1.f / HD);
    float var = r2[0] * (1.f / HD) - m * m;
    float inv = rsqrtf(var + EPS_);
    if (c < HD) {
        float o = (val - m) * inv * g[c] + bb[c];
        size_t off = ((size_t)h * NTOKS + tok) * HD + c;
        if (which == 0)      { qp[off] = o; qbb[off] = f2b(o * SCALE_); }
        else if (which == 1) { kx[((size_t)h * NTOKS + tok) * KCH + c] = f2b(o); }
        else                 { vbb[off] = f2b(o); }
    }
}

// ------------- Kernel 2b: transpose V to [h][c][tok] + write one-hot K channels -------------
__global__ __launch_bounds__(256) void vtrans(
    const u16* __restrict__ vbb, u16* __restrict__ vbT, u16* __restrict__ kx)
{
    __shared__ u16 tls[128][104];
    int h  = blockIdx.y;
    int t0 = blockIdx.x * 128;
    int tid = threadIdx.x;
    #pragma unroll
    for (int it = 0; it < 24; ++it) {           // 128*48 dwords
        int idx = tid + it * 256;
        int row = idx / 48, col = idx % 48;
        int tok = t0 + row; if (tok > NTOKS - 1) tok = NTOKS - 1;
        *(u32*)&tls[row][col*2] = *(const u32*)(vbb + ((size_t)h * NTOKS + tok) * HD + col*2);
    }
    __syncthreads();
    #pragma unroll
    for (int it = 0; it < 24; ++it) {           // 96*64 dwords
        int idx = tid + it * 256;
        int c = idx / 64, tp = idx % 64;
        u32 lo = tls[tp*2][c], hi = tls[tp*2+1][c];
        *(u32*)(vbT + ((size_t)h * HD + c) * VT_LD + t0 + tp*2) = lo | (hi << 16);
    }
    // one-hot bias channels for this head's kx rows
    #pragma unroll
    for (int it = 0; it < 32; ++it) {           // 128*64 u16
        int i = tid + it * 256;
        int tok = t0 + (i >> 6);
        int j = i & 63;
        if (tok >= NTOKS) continue;
        u16 v = 0;
        if (tok >= 1) {
            int sp  = tok - 1;
            int kt  = sp / (H_ * W_);
            int rem = sp % (H_ * W_);
            int kh  = rem / W_;
            int kw  = rem % W_;
            int match = (j < 8) ? (j == kt) : (j < 36) ? (j - 8 == kh) : (j - 36 == kw);
            v = match ? (u16)0x3F80 : (u16)0;   // bf16 1.0
        }
        kx[((size_t)h * NTOKS + tok) * KCH + 96 + j] = v;
    }
}

// ------------- Kernel 3: rel-pos bias component dot products (float4) -------------
__global__ __launch_bounds__(64) void relbias(
    const float* __restrict__ qp,
    const float* __restrict__ rel_h, const float* __restrict__ rel_w,
    const float* __restrict__ rel_t,
    float* __restrict__ bt, float* __restrict__ bh, float* __restrict__ bw)
{
    int h  = blockIdx.x / NSP;
    int sp = blockIdx.x % NSP;
    __shared__ float4 qv4[24];
    int t = threadIdx.x;
    if (t < 24)
        qv4[t] = ((const float4*)(qp + ((size_t)h * NTOKS + sp + 1) * HD))[t];
    __syncthreads();
    int tq  = sp / (H_ * W_);
    int rem = sp % (H_ * W_);
    int hq  = rem / W_;
    int wq  = rem % W_;
    const float* row;
    float* outp;
    if (t < 8)       { row = rel_t + (size_t)(tq - t        + (T_ - 1)) * HD; outp = bt + ((size_t)h*NSP + sp)*8  + t;      }
    else if (t < 36) { row = rel_h + (size_t)(hq - (t - 8)  + (H_ - 1)) * HD; outp = bh + ((size_t)h*NSP + sp)*28 + (t-8);  }
    else             { row = rel_w + (size_t)(wq - (t - 36) + (W_ - 1)) * HD; outp = bw + ((size_t)h*NSP + sp)*28 + (t-36); }
    const float4* r4 = (const float4*)row;
    float acc = 0.f;
    #pragma unroll
    for (int i = 0; i < 24; ++i) {
        float4 a = qv4[i], b = r4[i];
        acc += a.x*b.x + a.y*b.y + a.z*b.z + a.w*b.w;
    }
    *outp = acc;
}

// ------------- Kernel 4: MFMA flash attention v4: double-buffered staging -------------
// grid.x = QB3*8; g=blockIdx.x&7 -> (h = g>>2, split = g&3); qb = blockIdx.x>>3.
__global__ __launch_bounds__(256, 2) void attn_mfma4(
    const u16* __restrict__ qbb, const u16* __restrict__ kx,
    const u16* __restrict__ vbT,
    const float* __restrict__ btp, const float* __restrict__ bhp,
    const float* __restrict__ bwp,
    float* __restrict__ pO, float* __restrict__ pl)
{
    __shared__ __align__(16) u16 kls[2][20 * 512];  // 40 KB
    __shared__ __align__(16) u16 vls[2][12 * 512];  // 24 KB
    __shared__ __align__(16) u16 pls[64 * 72];      //  9 KB

    const int g     = blockIdx.x & 7;
    const int qb    = blockIdx.x >> 3;
    const int h     = g >> 2;
    const int split = g & 3;
    const int q0    = qb * QT;
    const int tid   = threadIdx.x;
    const int w     = tid >> 6;
    const int lane  = tid & 63;
    const int quad  = lane >> 4;
    const int l16   = lane & 15;

    const int t0 = split * 25;
    const int t1 = (t0 + 25 < NTILES_TOT) ? t0 + 25 : NTILES_TOT;

    // ---- staging helper: 8 async16 per wave into buffer `buf` ----
    auto stage = [&](int buf, int tile) {
        int kb0 = tile * KT;
        int key = kb0 + lane; if (key > NTOKS - 1) key = NTOKS - 1;
        const u16* gbase = kx + ((size_t)h * NTOKS + key) * KCH;
        #pragma unroll
        for (int i = 0; i < 5; ++i) {
            int CH = w * 5 + i;
            int c5 = CH >> 2, qd = CH & 3;
            async16(gbase + c5 * 32 + qd * 8, kls[buf] + CH * 512);
        }
        #pragma unroll
        for (int i = 0; i < 3; ++i) {
            int CH2 = w * 3 + i;
            int E = CH2 * 64 + lane;
            int kcq = E / 96, n = E - kcq * 96;
            int kc = kcq >> 2, qd = kcq & 3;
            const u16* src = vbT + ((size_t)h * HD + n) * VT_LD + kb0 + kc * 32 + qd * 8;
            async16(src, vls[buf] + CH2 * 512);
        }
    };

    stage(0, t0);   // prefetch first tile, then overlap aq build with its latency

    // A fragments: chunks 0..2 = q*SCALE (bf16 from qbb), 3..4 = bias (direct gather)
    bf16x8 aq[5];
    {
        int tokc = q0 + w * 16 + l16;
        int tq = tokc > NTOKS - 1 ? NTOKS - 1 : tokc;
        const u16* qrow = qbb + ((size_t)h * NTOKS + tq) * HD;
        #pragma unroll
        for (int cc = 0; cc < 3; ++cc)
            aq[cc] = *(const bf16x8*)(qrow + cc * 32 + quad * 8);
        bool has = (tokc >= 1 && tokc < NTOKS);
        int sp = tokc - 1;
        #pragma unroll
        for (int cc = 3; cc < 5; ++cc) {
            bf16x8 tf;
            #pragma unroll
            for (int j = 0; j < 8; ++j) {
                int kk = (cc - 3) * 32 + quad * 8 + j;
                float v = 0.f;
                if (has) {
                    if (kk < 8)       v = btp[((size_t)h * NSP + sp) * 8  + kk];
                    else if (kk < 36) v = bhp[((size_t)h * NSP + sp) * 28 + (kk - 8)];
                    else              v = bwp[((size_t)h * NSP + sp) * 28 + (kk - 36)];
                }
                tf[j] = (short)f2b(v);
            }
            aq[cc] = tf;
        }
    }

    f32x4 accO[6];
    #pragma unroll
    for (int nt = 0; nt < 6; ++nt) accO[nt] = (f32x4){0,0,0,0};
    float psum[4] = {0.f, 0.f, 0.f, 0.f};

    for (int tile = t0; tile < t1; ++tile) {
        const int cur = (tile - t0) & 1;
        __syncthreads();                       // stage(tile) landed; prior tile's reads done
        if (tile + 1 < t1) stage(cur ^ 1, tile + 1);   // prefetch next under this compute
        const int kb0 = tile * KT;
        const u16* kcur = kls[cur];
        const u16* vcur = vls[cur];
        // ---- S = scale*QK^T + bias: 4 n-tiles x 5 chunks = 20 MFMA/wave ----
        f32x4 sacc[4];
        #pragma unroll
        for (int nt = 0; nt < 4; ++nt) sacc[nt] = (f32x4){0,0,0,0};
        #pragma unroll
        for (int cc = 0; cc < 5; ++cc) {
            #pragma unroll
            for (int nt = 0; nt < 4; ++nt) {
                bf16x8 bk = *(const bf16x8*)(kcur + (((cc * 4 + quad) * 64) + nt * 16 + l16) * 8);
                sacc[nt] = __builtin_amdgcn_mfma_f32_16x16x32_bf16(aq[cc], bk, sacc[nt], 0, 0, 0);
            }
        }
        // ---- fixed-max softmax in-register; write wave-private P rows ----
        #pragma unroll
        for (int nt = 0; nt < 4; ++nt) {
            int keyg = kb0 + nt * 16 + l16;
            bool ok = keyg < NTOKS;
            #pragma unroll
            for (int rr = 0; rr < 4; ++rr) {
                float p = ok ? __expf(sacc[nt][rr]) : 0.f;
                psum[rr] += p;
                pls[(w * 16 + quad * 4 + rr) * 72 + nt * 16 + l16] = f2b(p);
            }
        }
        // ---- PV: 6 n-tiles x 2 k-chunks = 12 MFMA/wave ----
        #pragma unroll
        for (int kc = 0; kc < 2; ++kc) {
            bf16x8 ap = *(const bf16x8*)(pls + (w * 16 + l16) * 72 + kc * 32 + quad * 8);
            #pragma unroll
            for (int nt = 0; nt < 6; ++nt) {
                bf16x8 bv = *(const bf16x8*)(vcur + (((kc * 4 + quad) * 96) + nt * 16 + l16) * 8);
                accO[nt] = __builtin_amdgcn_mfma_f32_16x16x32_bf16(ap, bv, accO[nt], 0, 0, 0);
            }
        }
    }

    // ---- l reduction across the 16 lanes sharing a row-group ----
    #pragma unroll
    for (int off = 1; off < 16; off <<= 1) {
        #pragma unroll
        for (int rr = 0; rr < 4; ++rr)
            psum[rr] += __shfl_xor(psum[rr], off);
    }
    const int sh = split * HEADS + h;
    if (l16 == 0) {
        #pragma unroll
        for (int rr = 0; rr < 4; ++rr) {
            int tok = q0 + w * 16 + quad * 4 + rr;
            if (tok < NTOKS)
                pl[(size_t)sh * NTOKS + tok] = psum[rr];
        }
    }
    // ---- dump unnormalized O partials ----
    #pragma unroll
    for (int rr = 0; rr < 4; ++rr) {
        int tok = q0 + w * 16 + quad * 4 + rr;
        if (tok >= NTOKS) continue;
        #pragma unroll
        for (int nt = 0; nt < 6; ++nt)
            pO[((size_t)sh * NTOKS + tok) * HD + nt * 16 + l16] = accO[nt][rr];
    }
}

// ------- Kernel 4b: combine k-split partials + residual -> bf16 pre -------
__global__ __launch_bounds__(256) void combine(
    const float* __restrict__ pO, const float* __restrict__ pl,
    const float* __restrict__ qp, u16* __restrict__ preb)
{
    int i = blockIdx.x * 256 + threadIdx.x;   // pair index: (tok, channel-pair)
    const int NP = NTOKS * 96;
    if (i >= NP) return;
    int tok = i / 96, dp = i - tok * 96;
    int d0 = dp * 2;                 // global channel (even), pair never crosses head
    int hh = d0 / HD, c0 = d0 - hh * HD;
    float l = 0.f, o0 = 0.f, o1 = 0.f;
    #pragma unroll
    for (int s = 0; s < NSPL; ++s) {
        l += pl[(size_t)(s * HEADS + hh) * NTOKS + tok];
        const float* pp = pO + ((size_t)(s * HEADS + hh) * NTOKS + tok) * HD + c0;
        o0 += pp[0]; o1 += pp[1];
    }
    float v0 = o0 / l, v1 = o1 / l;
    if (tok >= 1) {
        const float* qq = qp + ((size_t)hh * NTOKS + tok) * HD + c0;
        v0 += qq[0]; v1 += qq[1];
    }
    u32 pack = (u32)f2b(v0) | ((u32)f2b(v1) << 16);
    *(u32*)(preb + (size_t)tok * DIM + d0) = pack;
}

extern "C" void kernel_launch(void* const* d_in, const int* in_sizes, int n_in,
                              void* d_out, int out_size, void* d_ws, size_t ws_size,
                              hipStream_t stream) {
    (void)in_sizes; (void)n_in; (void)out_size; (void)ws_size;
    const float* x      = (const float*)d_in[0];
    const float* qkv_w  = (const float*)d_in[1];
    const float* qkv_b  = (const float*)d_in[2];
    const float* proj_w = (const float*)d_in[3];
    const float* proj_b = (const float*)d_in[4];
    const float* pool_q = (const float*)d_in[5];
    const float* pool_k = (const float*)d_in[6];
    const float* pool_v = (const float*)d_in[7];
    const float* gq     = (const float*)d_in[8];
    const float* bq     = (const float*)d_in[9];
    const float* gk     = (const float*)d_in[10];
    const float* bk     = (const float*)d_in[11];
    const float* gv     = (const float*)d_in[12];
    const float* bv     = (const float*)d_in[13];
    const float* rel_h  = (const float*)d_in[14];
    const float* rel_w  = (const float*)d_in[15];
    const float* rel_t  = (const float*)d_in[16];

    char* p = (char*)d_ws;
    auto alloc = [&](size_t bytes) -> void* {
        void* r = (void*)p; p += (bytes + 255) & ~(size_t)255; return r;
    };
    float* qkv = (float*)alloc((size_t)NTOKS * 576 * 4);
    float* qp  = (float*)alloc((size_t)HEADS * NTOKS * HD * 4);
    u16*   qbb = (u16*)  alloc((size_t)HEADS * NTOKS * HD * 2);
    u16*   kxb = (u16*)  alloc((size_t)HEADS * NTOKS * KCH * 2);
    u16*   vbb = (u16*)  alloc((size_t)HEADS * NTOKS * HD * 2);
    u16*   vbT = (u16*)  alloc((size_t)HEADS * HD * VT_LD * 2);
    float* bt  = (float*)alloc((size_t)HEADS * NSP * 8 * 4);
    float* bh  = (float*)alloc((size_t)HEADS * NSP * 28 * 4);
    float* bw  = (float*)alloc((size_t)HEADS * NSP * 28 * 4);
    float* pO  = (float*)alloc((size_t)NSPL * HEADS * NTOKS * HD * 4);
    float* pl  = (float*)alloc((size_t)NSPL * HEADS * NTOKS * 4);
    u16*   xb  = (u16*)  alloc((size_t)NTOKS * DIM * 2);
    u16*   qwb = (u16*)  alloc((size_t)576 * DIM * 2);
    u16*   pwb = (u16*)  alloc((size_t)DIM * DIM * 2);
    u16*   preb= (u16*)  alloc((size_t)NTOKS * DIM * 2);

    const int nx = NTOKS * DIM, nqw = 576 * DIM, npw = DIM * DIM;
    cvt_bf16<<<1024, 256, 0, stream>>>(x, xb, nx, qkv_w, qwb, nqw, proj_w, pwb, npw);
    gemm_bf16<<<dim3(QB3, 9), 256, 0, stream>>>(xb, qwb, qkv_b, qkv, NTOKS, 576);
    pool_ln<<<dim3(HEADS * NTOKS, 3), 128, 0, stream>>>(
        qkv, pool_q, pool_k, pool_v, gq, bq, gk, bk, gv, bv, qp, qbb, kxb, vbb);
    vtrans<<<dim3((NTOKS + 127) / 128, HEADS), 256, 0, stream>>>(vbb, vbT, kxb);
    relbias<<<HEADS * NSP, 64, 0, stream>>>(qp, rel_h, rel_w, rel_t, bt, bh, bw);
    attn_mfma4<<<QB3 * 8, 256, 0, stream>>>(qbb, kxb, vbT, bt, bh, bw, pO, pl);
    combine<<<(NTOKS * 96 + 255) / 256, 256, 0, stream>>>(pO, pl, qp, preb);
    gemm_bf16<<<dim3(QB3, 3), 256, 0, stream>>>(preb, pwb, proj_b, (float*)d_out, NTOKS, 192);
}